// Round 10
// baseline (327.492 us; speedup 1.0000x reference)
//
#include <hip/hip_runtime.h>
#include <hip/hip_bf16.h>

#define E_EDGES 800000
#define NNODES  50000
#define HID     128

typedef __bf16 bf16x8 __attribute__((ext_vector_type(8)));
typedef float  f32x4  __attribute__((ext_vector_type(4)));
typedef unsigned short ushortx8 __attribute__((ext_vector_type(8)));

__device__ __forceinline__ unsigned short f2bf(float f) {   // RTNE
    union { float f; unsigned u; } v; v.f = f;
    unsigned r = v.u + 0x7FFFu + ((v.u >> 16) & 1u);
    return (unsigned short)(r >> 16);
}
__device__ __forceinline__ unsigned short f2bf_fast(float f) { // round-half-up
    union { float f; unsigned u; } v; v.f = f;
    return (unsigned short)((v.u + 0x8000u) >> 16);
}
__device__ __forceinline__ float bf2f(unsigned u16) {
    union { unsigned u; float f; } v; v.u = u16 << 16;
    return v.f;
}
// silu without IEEE-divide expansion: mul, exp, add, rcp, mul
__device__ __forceinline__ float silu_fast(float x) {
    float e = __expf(-x);
    return x * __builtin_amdgcn_rcpf(1.0f + e);
}

// ---- prep: weight packing + out:=coord + zero sort counters ----
__global__ void prep(const float* __restrict__ W1, const float* __restrict__ b1,
                     const float* __restrict__ W2, const float* __restrict__ b2,
                     const float* __restrict__ W3,
                     const float* __restrict__ coord, float* __restrict__ out,
                     unsigned short* __restrict__ W1p, unsigned short* __restrict__ W2p,
                     float4* __restrict__ Wext, float2* __restrict__ W3b2,
                     float2* __restrict__ Eea, unsigned* __restrict__ cnt) {
    int i = blockIdx.x * 256 + threadIdx.x;
    if (i < 3 * NNODES) out[i] = coord[i];
    if (cnt && i < 50176) cnt[i] = 0;
    if (i < 32768) {
        int j = i & 7, lane = (i >> 3) & 63, nt = (i >> 9) & 7, kc = i >> 12;
        int n = lane & 15, quad = lane >> 4;
        int k = kc * 32 + quad * 8 + j;
        W1p[i] = f2bf(W1[(nt * 16 + n) * 258 + k]);
    } else if (i < 49152) {
        int t = i - 32768;
        int j = t & 7, lane = (t >> 3) & 63, nt = (t >> 9) & 7, kc = t >> 12;
        int n = lane & 15, quad = lane >> 4;
        int p = kc * 32 + quad * 8 + j;
        int f = (p & 7) * 16 + (p >> 3);
        W2p[t] = f2bf(W2[(nt * 16 + n) * 128 + f]);
    } else if (i < 49280) {
        int c = i - 49152;
        Wext[c] = make_float4(W1[c * 258 + 256], W1[c * 258 + 257], b1[c], b2[c]);
    } else if (i < 49408) {
        int c = i - 49280;
        W3b2[c] = make_float2(W3[c], b2[c]);
    } else if (i < 49536) {
        int p = i - 49408;
        int f = (p & 7) * 16 + (p >> 3);
        Eea[p] = make_float2(W1[f * 258 + 256], W1[f * 258 + 257]);
    }
}

// ---- counting sort by row: histogram ----
__global__ void sort_hist(const int* __restrict__ ei, unsigned* __restrict__ cnt) {
    int e = blockIdx.x * 256 + threadIdx.x;
    if (e < E_EDGES) atomicAdd(&cnt[ei[e]], 1u);
}

// ---- single-block exclusive scan over 50176 bins (1024 thr x 49 bins) ----
__global__ void sort_scan(unsigned* __restrict__ cnt) {
    __shared__ unsigned tot[1024];
    const int t = threadIdx.x;
    unsigned s = 0;
    for (int i = 0; i < 49; ++i) s += cnt[t * 49 + i];
    tot[t] = s;
    __syncthreads();
    for (int off = 1; off < 1024; off <<= 1) {
        unsigned v = (t >= off) ? tot[t - off] : 0u;
        __syncthreads();
        tot[t] += v;
        __syncthreads();
    }
    unsigned run = tot[t] - s;   // exclusive base for this thread's chunk
    for (int i = 0; i < 49; ++i) {
        unsigned old = cnt[t * 49 + i];
        cnt[t * 49 + i] = run;
        run += old;
    }
}

// ---- scatter into sorted records: {row|col<<16, eax|eay (bf16), c0|c1, c2} ----
__global__ void sort_scatter(const int* __restrict__ ei, const float2* __restrict__ eattr,
                             const float* __restrict__ cdiff,
                             unsigned* __restrict__ cnt, uint4* __restrict__ sRec) {
    int e = blockIdx.x * 256 + threadIdx.x;
    if (e >= E_EDGES) return;
    int r = ei[e], c = ei[E_EDGES + e];
    unsigned pos = atomicAdd(&cnt[r], 1u);
    float2 ea = eattr[e];
    float c0 = cdiff[3 * (long)e + 0];
    float c1 = cdiff[3 * (long)e + 1];
    float c2 = cdiff[3 * (long)e + 2];
    sRec[pos] = make_uint4((unsigned)r | ((unsigned)c << 16),
                           (unsigned)f2bf(ea.x) | ((unsigned)f2bf(ea.y) << 16),
                           (unsigned)f2bf(c0) | ((unsigned)f2bf(c1) << 16),
                           (unsigned)f2bf(c2));
}

// ---- node projection, P and Q fused (r7/r8 validated) ----
__launch_bounds__(256)
__global__ void node_gemm_f(const float* __restrict__ h,
                            const ushortx8* __restrict__ W1p,
                            const float* __restrict__ b1,
                            unsigned short* __restrict__ PQb) {
    const int w    = threadIdx.x >> 6;
    const int lane = threadIdx.x & 63;
    const int n    = lane & 15;
    const int quad = lane >> 4;
    const int base = (blockIdx.x * 4 + w) * 16;

    int nodeA = base + n;
    if (nodeA >= NNODES) nodeA = NNODES - 1;

    const f32x4 zero = { 0.f, 0.f, 0.f, 0.f };
    f32x4 accP[8], accQ[8];
#pragma unroll
    for (int nt = 0; nt < 8; ++nt) { accP[nt] = zero; accQ[nt] = zero; }

#pragma unroll
    for (int kc = 0; kc < 4; ++kc) {
        const float* p = h + (long)nodeA * HID + kc * 32 + quad * 8;
        float4 lo = *(const float4*)p;
        float4 hi = *(const float4*)(p + 4);
        ushortx8 uu;
        uu[0] = f2bf(lo.x); uu[1] = f2bf(lo.y); uu[2] = f2bf(lo.z); uu[3] = f2bf(lo.w);
        uu[4] = f2bf(hi.x); uu[5] = f2bf(hi.y); uu[6] = f2bf(hi.z); uu[7] = f2bf(hi.w);
        bf16x8 af = __builtin_bit_cast(bf16x8, uu);
#pragma unroll
        for (int nt = 0; nt < 8; ++nt) {
            bf16x8 bP = __builtin_bit_cast(bf16x8, W1p[(kc * 8 + nt) * 64 + lane]);
            bf16x8 bQ = __builtin_bit_cast(bf16x8, W1p[((4 + kc) * 8 + nt) * 64 + lane]);
            accP[nt] = __builtin_amdgcn_mfma_f32_16x16x32_bf16(af, bP, accP[nt], 0, 0, 0);
            accQ[nt] = __builtin_amdgcn_mfma_f32_16x16x32_bf16(af, bQ, accQ[nt], 0, 0, 0);
        }
    }

    float b1v[8];
#pragma unroll
    for (int nt = 0; nt < 8; ++nt) b1v[nt] = b1[nt * 16 + n];

#pragma unroll
    for (int r = 0; r < 4; ++r) {
        int node = base + quad * 4 + r;
        if (node < NNODES) {
            ushortx8 uP, uQ;
#pragma unroll
            for (int nt = 0; nt < 8; ++nt) {
                uP[nt] = f2bf(accP[nt][r] + b1v[nt]);   // stored at p = n*8+nt
                uQ[nt] = f2bf(accQ[nt][r]);
            }
            *(ushortx8*)(PQb + (long)node * 256 + n * 8) = uP;
            *(ushortx8*)(PQb + (long)node * 256 + 128 + n * 8) = uQ;
        }
    }
}

// ---- edge kernel over row-sorted records: r5 shape (1 tile/wave, 50000 waves) ----
// Sorted rows => P-gathers broadcast/L1-hit; segmented epilogue => ~6x fewer atomics.
__launch_bounds__(256)
__global__ void edge_srt(const unsigned short* __restrict__ PQb,
                         const uint4* __restrict__ sRec,
                         const ushortx8* __restrict__ W2p,
                         const float4* __restrict__ Eea4,
                         const float2* __restrict__ W3b2,
                         float* __restrict__ out) {
    const int lane = threadIdx.x & 63;
    const int n    = lane & 15;
    const int quad = lane >> 4;
    const int tile = blockIdx.x * 4 + (threadIdx.x >> 6);

    uint4 rec = sRec[tile * 16 + n];           // lane (n,quad) holds edge n's record
    const int   ri_ = (int)(rec.x & 0xFFFFu);
    const int   ci_ = (int)(rec.x >> 16);
    const float eax = bf2f(rec.y & 0xFFFFu);
    const float eay = bf2f(rec.y >> 16);

    const unsigned short* Pb = PQb + (long)ri_ * 256 + quad * 8;
    const unsigned short* Qb = PQb + (long)ci_ * 256 + 128 + quad * 8;

    ushortx8 pf[4], qf[4];
#pragma unroll
    for (int kc = 0; kc < 4; ++kc) {
        pf[kc] = *(const ushortx8*)(Pb + kc * 32);
        qf[kc] = *(const ushortx8*)(Qb + kc * 32);
    }

    const f32x4 zero = { 0.f, 0.f, 0.f, 0.f };
    f32x4 acc[8];
#pragma unroll
    for (int nt = 0; nt < 8; ++nt) acc[nt] = zero;

#pragma unroll
    for (int kc = 0; kc < 4; ++kc) {
        float4 ef[4];
#pragma unroll
        for (int q2 = 0; q2 < 4; ++q2) ef[q2] = Eea4[kc * 16 + quad * 4 + q2];
        ushortx8 u;
#pragma unroll
        for (int j = 0; j < 8; ++j) {
            float ex = (j & 1) ? ef[j >> 1].z : ef[j >> 1].x;
            float ey = (j & 1) ? ef[j >> 1].w : ef[j >> 1].y;
            float v = bf2f(pf[kc][j]) + bf2f(qf[kc][j]) + eax * ex + eay * ey;
            u[j] = f2bf_fast(silu_fast(v));
        }
        bf16x8 af = __builtin_bit_cast(bf16x8, u);
#pragma unroll
        for (int nt = 0; nt < 8; ++nt) {
            bf16x8 bf = __builtin_bit_cast(bf16x8, W2p[(kc * 8 + nt) * 64 + lane]);
            acc[nt] = __builtin_amdgcn_mfma_f32_16x16x32_bf16(af, bf, acc[nt], 0, 0, 0);
        }
    }

    // layer 3: silu(acc + b2) . W3, butterfly over n
    float part[4] = { 0.f, 0.f, 0.f, 0.f };
#pragma unroll
    for (int nt = 0; nt < 8; ++nt) {
        float2 wb = W3b2[nt * 16 + n];   // {W3, b2}
#pragma unroll
        for (int r = 0; r < 4; ++r)
            part[r] += silu_fast(acc[nt][r] + wb.y) * wb.x;
    }
#pragma unroll
    for (int mask = 1; mask < 16; mask <<= 1)
#pragma unroll
        for (int r = 0; r < 4; ++r)
            part[r] += __shfl_xor(part[r], mask, 64);

    float s = 0.f;
#pragma unroll
    for (int r = 0; r < 4; ++r) {
        float t2 = __shfl(part[r], ((lane & 15) >> 2) * 16, 64);
        if ((lane & 3) == r) s = t2;
    }

    // epilogue: lane l<16 owns edge l; rows sorted -> segmented suffix reduction,
    // run leaders issue the atomics.
    float ex2 = __expf(2.0f * s);
    float tt = (1.0f - 2.0f * __builtin_amdgcn_rcpf(ex2 + 1.0f)) * 0.15f;  // tanh*0.15
    float v0 = bf2f(rec.z & 0xFFFFu) * tt;
    float v1 = bf2f(rec.z >> 16) * tt;
    float v2 = bf2f(rec.w & 0xFFFFu) * tt;

    int riv = (lane < 16) ? ri_ : -1;
    if (lane >= 16) { v0 = 0.f; v1 = 0.f; v2 = 0.f; }
#pragma unroll
    for (int step = 1; step < 16; step <<= 1) {
        int   rn = __shfl(riv, lane + step, 64);
        float a0 = __shfl(v0, lane + step, 64);
        float a1 = __shfl(v1, lane + step, 64);
        float a2 = __shfl(v2, lane + step, 64);
        if (rn == riv) { v0 += a0; v1 += a1; v2 += a2; }   // sorted: endpoint eq => run eq
    }
    int riPrev = __shfl(riv, lane - 1, 64);   // lane 0 reads lane 63 (riv=-1) -> leader
    if (lane < 16 && riPrev != riv) {
        atomicAdd(&out[riv * 3 + 0], v0);
        atomicAdd(&out[riv * 3 + 1], v1);
        atomicAdd(&out[riv * 3 + 2], v2);
    }
}

// ---- fallback (ws too small): round-5 validated ----
__launch_bounds__(256)
__global__ void edge_fb(const float* __restrict__ h, const int* __restrict__ ei,
                        const float* __restrict__ cdiff, const float* __restrict__ eattr,
                        const ushortx8* __restrict__ W1p, const ushortx8* __restrict__ W2p,
                        const float4* __restrict__ Wext, const float* __restrict__ W3,
                        float* __restrict__ out) {
    __shared__ __align__(16) unsigned short x1[4][32][136];
    __shared__ int   rowi[4][32];
    __shared__ int   coli[4][32];
    __shared__ float ea0[4][32];
    __shared__ float ea1[4][32];
    __shared__ float sbuf[4][32];

    const int w = threadIdx.x >> 6, lane = threadIdx.x & 63;
    const int n = lane & 15, quad = lane >> 4;
    const int ebase = (blockIdx.x * 4 + w) * 32;

    if (lane < 32) {
        int e = ebase + lane;
        rowi[w][lane] = ei[e];
        coli[w][lane] = ei[E_EDGES + e];
        const float2 ea = *(const float2*)(eattr + 2 * (long)e);
        ea0[w][lane] = ea.x; ea1[w][lane] = ea.y;
    }
    __syncthreads();

    int nodeR[2] = { rowi[w][n], rowi[w][16 + n] };
    int nodeC[2] = { coli[w][n], coli[w][16 + n] };

    const f32x4 zero = { 0.f, 0.f, 0.f, 0.f };
    f32x4 acc[2][8];
#pragma unroll
    for (int mt = 0; mt < 2; ++mt)
#pragma unroll
        for (int nt = 0; nt < 8; ++nt) acc[mt][nt] = zero;

#pragma unroll
    for (int kc = 0; kc < 8; ++kc) {
        bf16x8 afrag[2];
#pragma unroll
        for (int mt = 0; mt < 2; ++mt) {
            int node = (kc < 4) ? nodeR[mt] : nodeC[mt];
            const float* p = h + (long)node * HID + (kc & 3) * 32 + quad * 8;
            float4 lo = *(const float4*)p;
            float4 hi = *(const float4*)(p + 4);
            ushortx8 u;
            u[0] = f2bf(lo.x); u[1] = f2bf(lo.y); u[2] = f2bf(lo.z); u[3] = f2bf(lo.w);
            u[4] = f2bf(hi.x); u[5] = f2bf(hi.y); u[6] = f2bf(hi.z); u[7] = f2bf(hi.w);
            afrag[mt] = __builtin_bit_cast(bf16x8, u);
        }
#pragma unroll
        for (int nt = 0; nt < 8; ++nt) {
            bf16x8 bfrag = __builtin_bit_cast(bf16x8, W1p[(kc * 8 + nt) * 64 + lane]);
            acc[0][nt] = __builtin_amdgcn_mfma_f32_16x16x32_bf16(afrag[0], bfrag, acc[0][nt], 0, 0, 0);
            acc[1][nt] = __builtin_amdgcn_mfma_f32_16x16x32_bf16(afrag[1], bfrag, acc[1][nt], 0, 0, 0);
        }
    }

    float b2v[8];
    {
        float4 wx[8];
#pragma unroll
        for (int nt = 0; nt < 8; ++nt) wx[nt] = Wext[nt * 16 + n];
#pragma unroll
        for (int nt = 0; nt < 8; ++nt) b2v[nt] = wx[nt].w;
#pragma unroll
        for (int mt = 0; mt < 2; ++mt) {
#pragma unroll
            for (int r = 0; r < 4; ++r) {
                int m = mt * 16 + quad * 4 + r;
                float a0 = ea0[w][m], a1 = ea1[w][m];
                ushortx8 u;
#pragma unroll
                for (int nt = 0; nt < 8; ++nt) {
                    float v = acc[mt][nt][r] + wx[nt].z + a0 * wx[nt].x + a1 * wx[nt].y;
                    u[nt] = f2bf(silu_fast(v));
                }
                *(ushortx8*)&x1[w][m][n * 8] = u;
            }
        }
    }
    __syncthreads();

#pragma unroll
    for (int mt = 0; mt < 2; ++mt)
#pragma unroll
        for (int nt = 0; nt < 8; ++nt) acc[mt][nt] = zero;

#pragma unroll
    for (int kc = 0; kc < 4; ++kc) {
        bf16x8 afrag[2];
#pragma unroll
        for (int mt = 0; mt < 2; ++mt)
            afrag[mt] = __builtin_bit_cast(bf16x8, *(const ushortx8*)&x1[w][mt * 16 + n][kc * 32 + quad * 8]);
#pragma unroll
        for (int nt = 0; nt < 8; ++nt) {
            bf16x8 bfrag = __builtin_bit_cast(bf16x8, W2p[(kc * 8 + nt) * 64 + lane]);
            acc[0][nt] = __builtin_amdgcn_mfma_f32_16x16x32_bf16(afrag[0], bfrag, acc[0][nt], 0, 0, 0);
            acc[1][nt] = __builtin_amdgcn_mfma_f32_16x16x32_bf16(afrag[1], bfrag, acc[1][nt], 0, 0, 0);
        }
    }

    float part[2][4] = { {0.f,0.f,0.f,0.f}, {0.f,0.f,0.f,0.f} };
#pragma unroll
    for (int nt = 0; nt < 8; ++nt) {
        float w3 = W3[nt * 16 + n];
#pragma unroll
        for (int mt = 0; mt < 2; ++mt)
#pragma unroll
            for (int r = 0; r < 4; ++r)
                part[mt][r] += silu_fast(acc[mt][nt][r] + b2v[nt]) * w3;
    }
#pragma unroll
    for (int mask = 1; mask < 16; mask <<= 1)
#pragma unroll
        for (int mt = 0; mt < 2; ++mt)
#pragma unroll
            for (int r = 0; r < 4; ++r)
                part[mt][r] += __shfl_xor(part[mt][r], mask, 64);

    if (n == 0) {
#pragma unroll
        for (int mt = 0; mt < 2; ++mt)
#pragma unroll
            for (int r = 0; r < 4; ++r)
                sbuf[w][mt * 16 + quad * 4 + r] = part[mt][r];
    }
    __syncthreads();

    if (lane < 32) {
        int e = ebase + lane;
        float s = sbuf[w][lane];
        float ex = __expf(2.0f * s);
        float t = (1.0f - 2.0f * __builtin_amdgcn_rcpf(ex + 1.0f)) * 0.15f;
        float c0 = cdiff[3 * (long)e + 0];
        float c1 = cdiff[3 * (long)e + 1];
        float c2 = cdiff[3 * (long)e + 2];
        int r = rowi[w][lane];
        atomicAdd(&out[r * 3 + 0], c0 * t);
        atomicAdd(&out[r * 3 + 1], c1 * t);
        atomicAdd(&out[r * 3 + 2], c2 * t);
    }
}

extern "C" void kernel_launch(void* const* d_in, const int* in_sizes, int n_in,
                              void* d_out, int out_size, void* d_ws, size_t ws_size,
                              hipStream_t stream) {
    const float* h     = (const float*)d_in[0];
    const float* coord = (const float*)d_in[1];
    const int*   ei    = (const int*)d_in[2];
    const float* cdiff = (const float*)d_in[3];
    const float* eattr = (const float*)d_in[4];
    const float* W1    = (const float*)d_in[5];
    const float* b1    = (const float*)d_in[6];
    const float* W2    = (const float*)d_in[7];
    const float* b2    = (const float*)d_in[8];
    const float* W3    = (const float*)d_in[9];
    float* out = (float*)d_out;

    char* ws = (char*)d_ws;
    unsigned short* W1p  = (unsigned short*)ws;                    // 65536 B
    unsigned short* W2p  = (unsigned short*)(ws + 65536);          // 32768 B
    float4*         Wext = (float4*)(ws + 98304);                  // 2048 B
    float2*         W3b2 = (float2*)(ws + 100352);                 // 1024 B
    float2*         Eea  = (float2*)(ws + 101376);                 // 1024 B
    unsigned short* PQb  = (unsigned short*)(ws + 102400);         // 25.6 MB
    uint4*          sRec = (uint4*)(ws + 102400 + 25600000);       // 12.8 MB
    unsigned*       cnt  = (unsigned*)(ws + 102400 + 25600000 + 12800000); // 200704 B
    const size_t need_full = 102400ull + 25600000ull + 12800000ull + 200704ull;

    const bool full = (ws_size >= need_full);

    prep<<<587, 256, 0, stream>>>(W1, b1, W2, b2, W3, coord, out,
                                  W1p, W2p, Wext, W3b2, Eea,
                                  full ? cnt : (unsigned*)nullptr);

    if (full) {
        sort_hist<<<3125, 256, 0, stream>>>(ei, cnt);
        sort_scan<<<1, 1024, 0, stream>>>(cnt);
        sort_scatter<<<3125, 256, 0, stream>>>(ei, (const float2*)eattr, cdiff, cnt, sRec);
        node_gemm_f<<<(NNODES + 63) / 64, 256, 0, stream>>>(h, (const ushortx8*)W1p, b1, PQb);
        // 12500 blocks x 4 waves x 16 edges = 800000 exactly
        edge_srt<<<E_EDGES / 64, 256, 0, stream>>>(PQb, sRec,
                                                   (const ushortx8*)W2p, (const float4*)Eea,
                                                   (const float2*)W3b2, out);
    } else {
        edge_fb<<<E_EDGES / 128, 256, 0, stream>>>(h, ei, cdiff, eattr,
                                                   (const ushortx8*)W1p, (const ushortx8*)W2p,
                                                   (const float4*)Wext, W3, out);
    }
}

// Round 11
// 312.359 us; speedup vs baseline: 1.0484x; 1.0484x over previous
//
#include <hip/hip_runtime.h>
#include <hip/hip_bf16.h>

#define E_EDGES 800000
#define NNODES  50000
#define HID     128

typedef __bf16 bf16x8 __attribute__((ext_vector_type(8)));
typedef float  f32x4  __attribute__((ext_vector_type(4)));
typedef unsigned short ushortx8 __attribute__((ext_vector_type(8)));

__device__ __forceinline__ unsigned short f2bf(float f) {   // RTNE
    union { float f; unsigned u; } v; v.f = f;
    unsigned r = v.u + 0x7FFFu + ((v.u >> 16) & 1u);
    return (unsigned short)(r >> 16);
}
__device__ __forceinline__ unsigned short f2bf_fast(float f) { // round-half-up
    union { float f; unsigned u; } v; v.f = f;
    return (unsigned short)((v.u + 0x8000u) >> 16);
}
__device__ __forceinline__ float bf2f(unsigned u16) {
    union { unsigned u; float f; } v; v.u = u16 << 16;
    return v.f;
}
// silu without IEEE-divide expansion: mul, exp, add, rcp, mul
__device__ __forceinline__ float silu_fast(float x) {
    float e = __expf(-x);
    return x * __builtin_amdgcn_rcpf(1.0f + e);
}

// ---- prep + histogram fused (cnt pre-zeroed by hipMemsetAsync) ----
__global__ void prep_hist(const float* __restrict__ W1, const float* __restrict__ b1,
                          const float* __restrict__ W2, const float* __restrict__ b2,
                          const float* __restrict__ W3,
                          const float* __restrict__ coord, float* __restrict__ out,
                          const int* __restrict__ ei,
                          unsigned short* __restrict__ W1p, unsigned short* __restrict__ W2p,
                          float4* __restrict__ Wext, float2* __restrict__ W3b2,
                          float2* __restrict__ Eea, unsigned* __restrict__ cnt) {
    int i = blockIdx.x * 256 + threadIdx.x;
    if (cnt && i < E_EDGES) atomicAdd(&cnt[ei[i]], 1u);
    if (i < 3 * NNODES) out[i] = coord[i];
    if (i < 32768) {
        int j = i & 7, lane = (i >> 3) & 63, nt = (i >> 9) & 7, kc = i >> 12;
        int n = lane & 15, quad = lane >> 4;
        int k = kc * 32 + quad * 8 + j;
        W1p[i] = f2bf(W1[(nt * 16 + n) * 258 + k]);
    } else if (i < 49152) {
        int t = i - 32768;
        int j = t & 7, lane = (t >> 3) & 63, nt = (t >> 9) & 7, kc = t >> 12;
        int n = lane & 15, quad = lane >> 4;
        int p = kc * 32 + quad * 8 + j;
        int f = (p & 7) * 16 + (p >> 3);
        W2p[t] = f2bf(W2[(nt * 16 + n) * 128 + f]);
    } else if (i < 49280) {
        int c = i - 49152;
        Wext[c] = make_float4(W1[c * 258 + 256], W1[c * 258 + 257], b1[c], b2[c]);
    } else if (i < 49408) {
        int c = i - 49280;
        W3b2[c] = make_float2(W3[c], b2[c]);
    } else if (i < 49536) {
        int p = i - 49408;
        int f = (p & 7) * 16 + (p >> 3);
        Eea[p] = make_float2(W1[f * 258 + 256], W1[f * 258 + 257]);
    }
}

// ---- multi-block scan, phase A: per-chunk exclusive scan (196 x 256 bins) ----
__global__ void scanA(unsigned* __restrict__ cnt, unsigned* __restrict__ chunkTot) {
    __shared__ unsigned sm[256];
    const int b = blockIdx.x, t = threadIdx.x;
    unsigned v = cnt[b * 256 + t];
    sm[t] = v;
    __syncthreads();
    unsigned x = v;
    for (int off = 1; off < 256; off <<= 1) {
        unsigned y = (t >= off) ? sm[t - off] : 0u;
        __syncthreads();
        x += y;
        sm[t] = x;
        __syncthreads();
    }
    cnt[b * 256 + t] = x - v;          // exclusive within chunk
    if (t == 255) chunkTot[b] = x;     // chunk total
}

// ---- scan phase B: add exclusive chunk base ----
__global__ void scanB(unsigned* __restrict__ cnt, const unsigned* __restrict__ chunkTot) {
    __shared__ unsigned sm[256];
    const int b = blockIdx.x, t = threadIdx.x;
    sm[t] = (t < b && t < 196) ? chunkTot[t] : 0u;
    __syncthreads();
    for (int off = 128; off > 0; off >>= 1) {
        if (t < off) sm[t] += sm[t + off];
        __syncthreads();
    }
    cnt[b * 256 + t] += sm[0];
}

// ---- fused: sorted-record scatter (blocks < 3125) + node projection (rest) ----
// node part: P/Q split across waves (6256 waves) for 2x memory-level parallelism.
__launch_bounds__(256)
__global__ void scatter_node(const int* __restrict__ ei, const float2* __restrict__ eattr,
                             const float* __restrict__ cdiff,
                             unsigned* __restrict__ cnt, uint4* __restrict__ sRec,
                             const float* __restrict__ h, const ushortx8* __restrict__ W1p,
                             const float* __restrict__ b1, unsigned short* __restrict__ PQb) {
    if (blockIdx.x < 3125) {
        int e = blockIdx.x * 256 + threadIdx.x;
        if (e >= E_EDGES) return;
        int r = ei[e], c = ei[E_EDGES + e];
        unsigned pos = atomicAdd(&cnt[r], 1u);
        float2 ea = eattr[e];
        float c0 = cdiff[3 * (long)e + 0];
        float c1 = cdiff[3 * (long)e + 1];
        float c2 = cdiff[3 * (long)e + 2];
        sRec[pos] = make_uint4((unsigned)r | ((unsigned)c << 16),
                               (unsigned)f2bf(ea.x) | ((unsigned)f2bf(ea.y) << 16),
                               (unsigned)f2bf(c0) | ((unsigned)f2bf(c1) << 16),
                               (unsigned)f2bf(c2));
        return;
    }

    // node projection: global wave id selects (nodeBase, half)
    const int lane = threadIdx.x & 63;
    const int n    = lane & 15;
    const int quad = lane >> 4;
    const int gw   = (blockIdx.x - 3125) * 4 + (threadIdx.x >> 6);  // 0..6255
    const int half = gw & 1;                                        // 0=P, 1=Q
    const int base = (gw >> 1) * 16;
    if (base >= NNODES) return;

    int nodeA = base + n;
    if (nodeA >= NNODES) nodeA = NNODES - 1;

    const f32x4 zero = { 0.f, 0.f, 0.f, 0.f };
    f32x4 acc[8];
#pragma unroll
    for (int nt = 0; nt < 8; ++nt) acc[nt] = zero;

#pragma unroll
    for (int kc = 0; kc < 4; ++kc) {
        const float* p = h + (long)nodeA * HID + kc * 32 + quad * 8;
        float4 lo = *(const float4*)p;
        float4 hi = *(const float4*)(p + 4);
        ushortx8 uu;
        uu[0] = f2bf(lo.x); uu[1] = f2bf(lo.y); uu[2] = f2bf(lo.z); uu[3] = f2bf(lo.w);
        uu[4] = f2bf(hi.x); uu[5] = f2bf(hi.y); uu[6] = f2bf(hi.z); uu[7] = f2bf(hi.w);
        bf16x8 af = __builtin_bit_cast(bf16x8, uu);
#pragma unroll
        for (int nt = 0; nt < 8; ++nt) {
            bf16x8 bf = __builtin_bit_cast(bf16x8, W1p[((half * 4 + kc) * 8 + nt) * 64 + lane]);
            acc[nt] = __builtin_amdgcn_mfma_f32_16x16x32_bf16(af, bf, acc[nt], 0, 0, 0);
        }
    }

    float b1v[8];
#pragma unroll
    for (int nt = 0; nt < 8; ++nt) b1v[nt] = (half == 0) ? b1[nt * 16 + n] : 0.f;

#pragma unroll
    for (int r = 0; r < 4; ++r) {
        int node = base + quad * 4 + r;
        if (node < NNODES) {
            ushortx8 u;
#pragma unroll
            for (int nt = 0; nt < 8; ++nt)
                u[nt] = f2bf(acc[nt][r] + b1v[nt]);   // stored at p = n*8+nt
            *(ushortx8*)(PQb + (long)node * 256 + half * 128 + n * 8) = u;
        }
    }
}

// ---- edge kernel over row-sorted records (r10 validated, byte-identical) ----
__launch_bounds__(256)
__global__ void edge_srt(const unsigned short* __restrict__ PQb,
                         const uint4* __restrict__ sRec,
                         const ushortx8* __restrict__ W2p,
                         const float4* __restrict__ Eea4,
                         const float2* __restrict__ W3b2,
                         float* __restrict__ out) {
    const int lane = threadIdx.x & 63;
    const int n    = lane & 15;
    const int quad = lane >> 4;
    const int tile = blockIdx.x * 4 + (threadIdx.x >> 6);

    uint4 rec = sRec[tile * 16 + n];           // lane (n,quad) holds edge n's record
    const int   ri_ = (int)(rec.x & 0xFFFFu);
    const int   ci_ = (int)(rec.x >> 16);
    const float eax = bf2f(rec.y & 0xFFFFu);
    const float eay = bf2f(rec.y >> 16);

    const unsigned short* Pb = PQb + (long)ri_ * 256 + quad * 8;
    const unsigned short* Qb = PQb + (long)ci_ * 256 + 128 + quad * 8;

    ushortx8 pf[4], qf[4];
#pragma unroll
    for (int kc = 0; kc < 4; ++kc) {
        pf[kc] = *(const ushortx8*)(Pb + kc * 32);
        qf[kc] = *(const ushortx8*)(Qb + kc * 32);
    }

    const f32x4 zero = { 0.f, 0.f, 0.f, 0.f };
    f32x4 acc[8];
#pragma unroll
    for (int nt = 0; nt < 8; ++nt) acc[nt] = zero;

#pragma unroll
    for (int kc = 0; kc < 4; ++kc) {
        float4 ef[4];
#pragma unroll
        for (int q2 = 0; q2 < 4; ++q2) ef[q2] = Eea4[kc * 16 + quad * 4 + q2];
        ushortx8 u;
#pragma unroll
        for (int j = 0; j < 8; ++j) {
            float ex = (j & 1) ? ef[j >> 1].z : ef[j >> 1].x;
            float ey = (j & 1) ? ef[j >> 1].w : ef[j >> 1].y;
            float v = bf2f(pf[kc][j]) + bf2f(qf[kc][j]) + eax * ex + eay * ey;
            u[j] = f2bf_fast(silu_fast(v));
        }
        bf16x8 af = __builtin_bit_cast(bf16x8, u);
#pragma unroll
        for (int nt = 0; nt < 8; ++nt) {
            bf16x8 bf = __builtin_bit_cast(bf16x8, W2p[(kc * 8 + nt) * 64 + lane]);
            acc[nt] = __builtin_amdgcn_mfma_f32_16x16x32_bf16(af, bf, acc[nt], 0, 0, 0);
        }
    }

    // layer 3: silu(acc + b2) . W3, butterfly over n
    float part[4] = { 0.f, 0.f, 0.f, 0.f };
#pragma unroll
    for (int nt = 0; nt < 8; ++nt) {
        float2 wb = W3b2[nt * 16 + n];   // {W3, b2}
#pragma unroll
        for (int r = 0; r < 4; ++r)
            part[r] += silu_fast(acc[nt][r] + wb.y) * wb.x;
    }
#pragma unroll
    for (int mask = 1; mask < 16; mask <<= 1)
#pragma unroll
        for (int r = 0; r < 4; ++r)
            part[r] += __shfl_xor(part[r], mask, 64);

    float s = 0.f;
#pragma unroll
    for (int r = 0; r < 4; ++r) {
        float t2 = __shfl(part[r], ((lane & 15) >> 2) * 16, 64);
        if ((lane & 3) == r) s = t2;
    }

    // epilogue: lane l<16 owns edge l; rows sorted -> segmented suffix reduction
    float ex2 = __expf(2.0f * s);
    float tt = (1.0f - 2.0f * __builtin_amdgcn_rcpf(ex2 + 1.0f)) * 0.15f;  // tanh*0.15
    float v0 = bf2f(rec.z & 0xFFFFu) * tt;
    float v1 = bf2f(rec.z >> 16) * tt;
    float v2 = bf2f(rec.w & 0xFFFFu) * tt;

    int riv = (lane < 16) ? ri_ : -1;
    if (lane >= 16) { v0 = 0.f; v1 = 0.f; v2 = 0.f; }
#pragma unroll
    for (int step = 1; step < 16; step <<= 1) {
        int   rn = __shfl(riv, lane + step, 64);
        float a0 = __shfl(v0, lane + step, 64);
        float a1 = __shfl(v1, lane + step, 64);
        float a2 = __shfl(v2, lane + step, 64);
        if (rn == riv) { v0 += a0; v1 += a1; v2 += a2; }
    }
    int riPrev = __shfl(riv, lane - 1, 64);
    if (lane < 16 && riPrev != riv) {
        atomicAdd(&out[riv * 3 + 0], v0);
        atomicAdd(&out[riv * 3 + 1], v1);
        atomicAdd(&out[riv * 3 + 2], v2);
    }
}

// ---- fallback (ws too small): round-5 validated ----
__launch_bounds__(256)
__global__ void edge_fb(const float* __restrict__ h, const int* __restrict__ ei,
                        const float* __restrict__ cdiff, const float* __restrict__ eattr,
                        const ushortx8* __restrict__ W1p, const ushortx8* __restrict__ W2p,
                        const float4* __restrict__ Wext, const float* __restrict__ W3,
                        float* __restrict__ out) {
    __shared__ __align__(16) unsigned short x1[4][32][136];
    __shared__ int   rowi[4][32];
    __shared__ int   coli[4][32];
    __shared__ float ea0[4][32];
    __shared__ float ea1[4][32];
    __shared__ float sbuf[4][32];

    const int w = threadIdx.x >> 6, lane = threadIdx.x & 63;
    const int n = lane & 15, quad = lane >> 4;
    const int ebase = (blockIdx.x * 4 + w) * 32;

    if (lane < 32) {
        int e = ebase + lane;
        rowi[w][lane] = ei[e];
        coli[w][lane] = ei[E_EDGES + e];
        const float2 ea = *(const float2*)(eattr + 2 * (long)e);
        ea0[w][lane] = ea.x; ea1[w][lane] = ea.y;
    }
    __syncthreads();

    int nodeR[2] = { rowi[w][n], rowi[w][16 + n] };
    int nodeC[2] = { coli[w][n], coli[w][16 + n] };

    const f32x4 zero = { 0.f, 0.f, 0.f, 0.f };
    f32x4 acc[2][8];
#pragma unroll
    for (int mt = 0; mt < 2; ++mt)
#pragma unroll
        for (int nt = 0; nt < 8; ++nt) acc[mt][nt] = zero;

#pragma unroll
    for (int kc = 0; kc < 8; ++kc) {
        bf16x8 afrag[2];
#pragma unroll
        for (int mt = 0; mt < 2; ++mt) {
            int node = (kc < 4) ? nodeR[mt] : nodeC[mt];
            const float* p = h + (long)node * HID + (kc & 3) * 32 + quad * 8;
            float4 lo = *(const float4*)p;
            float4 hi = *(const float4*)(p + 4);
            ushortx8 u;
            u[0] = f2bf(lo.x); u[1] = f2bf(lo.y); u[2] = f2bf(lo.z); u[3] = f2bf(lo.w);
            u[4] = f2bf(hi.x); u[5] = f2bf(hi.y); u[6] = f2bf(hi.z); u[7] = f2bf(hi.w);
            afrag[mt] = __builtin_bit_cast(bf16x8, u);
        }
#pragma unroll
        for (int nt = 0; nt < 8; ++nt) {
            bf16x8 bfrag = __builtin_bit_cast(bf16x8, W1p[(kc * 8 + nt) * 64 + lane]);
            acc[0][nt] = __builtin_amdgcn_mfma_f32_16x16x32_bf16(afrag[0], bfrag, acc[0][nt], 0, 0, 0);
            acc[1][nt] = __builtin_amdgcn_mfma_f32_16x16x32_bf16(afrag[1], bfrag, acc[1][nt], 0, 0, 0);
        }
    }

    float b2v[8];
    {
        float4 wx[8];
#pragma unroll
        for (int nt = 0; nt < 8; ++nt) wx[nt] = Wext[nt * 16 + n];
#pragma unroll
        for (int nt = 0; nt < 8; ++nt) b2v[nt] = wx[nt].w;
#pragma unroll
        for (int mt = 0; mt < 2; ++mt) {
#pragma unroll
            for (int r = 0; r < 4; ++r) {
                int m = mt * 16 + quad * 4 + r;
                float a0 = ea0[w][m], a1 = ea1[w][m];
                ushortx8 u;
#pragma unroll
                for (int nt = 0; nt < 8; ++nt) {
                    float v = acc[mt][nt][r] + wx[nt].z + a0 * wx[nt].x + a1 * wx[nt].y;
                    u[nt] = f2bf(silu_fast(v));
                }
                *(ushortx8*)&x1[w][m][n * 8] = u;
            }
        }
    }
    __syncthreads();

#pragma unroll
    for (int mt = 0; mt < 2; ++mt)
#pragma unroll
        for (int nt = 0; nt < 8; ++nt) acc[mt][nt] = zero;

#pragma unroll
    for (int kc = 0; kc < 4; ++kc) {
        bf16x8 afrag[2];
#pragma unroll
        for (int mt = 0; mt < 2; ++mt)
            afrag[mt] = __builtin_bit_cast(bf16x8, *(const ushortx8*)&x1[w][mt * 16 + n][kc * 32 + quad * 8]);
#pragma unroll
        for (int nt = 0; nt < 8; ++nt) {
            bf16x8 bfrag = __builtin_bit_cast(bf16x8, W2p[(kc * 8 + nt) * 64 + lane]);
            acc[0][nt] = __builtin_amdgcn_mfma_f32_16x16x32_bf16(afrag[0], bfrag, acc[0][nt], 0, 0, 0);
            acc[1][nt] = __builtin_amdgcn_mfma_f32_16x16x32_bf16(afrag[1], bfrag, acc[1][nt], 0, 0, 0);
        }
    }

    float part[2][4] = { {0.f,0.f,0.f,0.f}, {0.f,0.f,0.f,0.f} };
#pragma unroll
    for (int nt = 0; nt < 8; ++nt) {
        float w3 = W3[nt * 16 + n];
#pragma unroll
        for (int mt = 0; mt < 2; ++mt)
#pragma unroll
            for (int r = 0; r < 4; ++r)
                part[mt][r] += silu_fast(acc[mt][nt][r] + b2v[nt]) * w3;
    }
#pragma unroll
    for (int mask = 1; mask < 16; mask <<= 1)
#pragma unroll
        for (int mt = 0; mt < 2; ++mt)
#pragma unroll
            for (int r = 0; r < 4; ++r)
                part[mt][r] += __shfl_xor(part[mt][r], mask, 64);

    if (n == 0) {
#pragma unroll
        for (int mt = 0; mt < 2; ++mt)
#pragma unroll
            for (int r = 0; r < 4; ++r)
                sbuf[w][mt * 16 + quad * 4 + r] = part[mt][r];
    }
    __syncthreads();

    if (lane < 32) {
        int e = ebase + lane;
        float s = sbuf[w][lane];
        float ex = __expf(2.0f * s);
        float t = (1.0f - 2.0f * __builtin_amdgcn_rcpf(ex + 1.0f)) * 0.15f;
        float c0 = cdiff[3 * (long)e + 0];
        float c1 = cdiff[3 * (long)e + 1];
        float c2 = cdiff[3 * (long)e + 2];
        int r = rowi[w][lane];
        atomicAdd(&out[r * 3 + 0], c0 * t);
        atomicAdd(&out[r * 3 + 1], c1 * t);
        atomicAdd(&out[r * 3 + 2], c2 * t);
    }
}

extern "C" void kernel_launch(void* const* d_in, const int* in_sizes, int n_in,
                              void* d_out, int out_size, void* d_ws, size_t ws_size,
                              hipStream_t stream) {
    const float* h     = (const float*)d_in[0];
    const float* coord = (const float*)d_in[1];
    const int*   ei    = (const int*)d_in[2];
    const float* cdiff = (const float*)d_in[3];
    const float* eattr = (const float*)d_in[4];
    const float* W1    = (const float*)d_in[5];
    const float* b1    = (const float*)d_in[6];
    const float* W2    = (const float*)d_in[7];
    const float* b2    = (const float*)d_in[8];
    const float* W3    = (const float*)d_in[9];
    float* out = (float*)d_out;

    char* ws = (char*)d_ws;
    unsigned short* W1p  = (unsigned short*)ws;                    // 65536 B
    unsigned short* W2p  = (unsigned short*)(ws + 65536);          // 32768 B
    float4*         Wext = (float4*)(ws + 98304);                  // 2048 B
    float2*         W3b2 = (float2*)(ws + 100352);                 // 1024 B
    float2*         Eea  = (float2*)(ws + 101376);                 // 1024 B
    unsigned short* PQb  = (unsigned short*)(ws + 102400);         // 25.6 MB
    uint4*          sRec = (uint4*)(ws + 102400 + 25600000);       // 12.8 MB
    unsigned*       cnt  = (unsigned*)(ws + 102400 + 25600000 + 12800000);   // 200704 B
    unsigned*       chunkTot = (unsigned*)(ws + 102400 + 25600000 + 12800000 + 200704); // 1024 B
    const size_t need_full = 102400ull + 25600000ull + 12800000ull + 200704ull + 1024ull;

    const bool full = (ws_size >= need_full);

    if (full) {
        hipMemsetAsync(cnt, 0, 50176 * sizeof(unsigned), stream);
        prep_hist<<<3125, 256, 0, stream>>>(W1, b1, W2, b2, W3, coord, out, ei,
                                            W1p, W2p, Wext, W3b2, Eea, cnt);
        scanA<<<196, 256, 0, stream>>>(cnt, chunkTot);
        scanB<<<196, 256, 0, stream>>>(cnt, chunkTot);
        // 3125 scatter blocks + 1564 node blocks (6256 waves, P/Q split)
        scatter_node<<<3125 + 1564, 256, 0, stream>>>(ei, (const float2*)eattr, cdiff,
                                                      cnt, sRec, h, (const ushortx8*)W1p,
                                                      b1, PQb);
        edge_srt<<<E_EDGES / 64, 256, 0, stream>>>(PQb, sRec,
                                                   (const ushortx8*)W2p, (const float4*)Eea,
                                                   (const float2*)W3b2, out);
    } else {
        prep_hist<<<587, 256, 0, stream>>>(W1, b1, W2, b2, W3, coord, out, ei,
                                           W1p, W2p, Wext, W3b2, Eea, (unsigned*)nullptr);
        edge_fb<<<E_EDGES / 128, 256, 0, stream>>>(h, ei, cdiff, eattr,
                                                   (const ushortx8*)W1p, (const ushortx8*)W2p,
                                                   (const float4*)Wext, W3, out);
    }
}